// Round 1
// baseline (281.260 us; speedup 1.0000x reference)
//
#include <hip/hip_runtime.h>
#include <hip/hip_bf16.h>

#define NN 50000
#define EE 800000
#define DD 128

typedef __attribute__((ext_vector_type(8))) short bf16x8;
typedef __attribute__((ext_vector_type(4))) float f32x4;

static __device__ __forceinline__ unsigned short f2bf(float f) {
  union { float f; unsigned u; } v; v.f = f;
  unsigned r = v.u + 0x7FFFu + ((v.u >> 16) & 1u);
  return (unsigned short)(r >> 16);
}

__global__ void k_zero_deg(int* deg) {
  int i = blockIdx.x * blockDim.x + threadIdx.x;
  if (i < NN) deg[i] = 0;
}

__global__ void k_deg(const int* dst, int* deg) {
  int e = blockIdx.x * blockDim.x + threadIdx.x;
  if (e < EE) atomicAdd(&deg[dst[e]], 1);
}

// Per-block inclusive scan (Hillis-Steele over 256)
__global__ void k_scan1(const int* deg, int* incl, int* bsum) {
  __shared__ int s[256];
  int t = threadIdx.x;
  int i = blockIdx.x * 256 + t;
  int v = (i < NN) ? deg[i] : 0;
  s[t] = v;
  for (int off = 1; off < 256; off <<= 1) {
    __syncthreads();
    int tmp = (t >= off) ? s[t - off] : 0;
    __syncthreads();
    if (t >= off) s[t] += tmp;
  }
  __syncthreads();
  if (i < NN) incl[i] = s[t];
  if (t == 255) bsum[blockIdx.x] = s[255];
}

__global__ void k_scan2(int* bsum, int nb) {
  __shared__ int s[256];
  int t = threadIdx.x;
  int v = (t < nb) ? bsum[t] : 0;
  s[t] = v;
  for (int off = 1; off < 256; off <<= 1) {
    __syncthreads();
    int tmp = (t >= off) ? s[t - off] : 0;
    __syncthreads();
    if (t >= off) s[t] += tmp;
  }
  if (t < nb) bsum[t] = s[t];
}

__global__ void k_scan3(const int* deg, const int* incl, const int* bsum,
                        int* rowStart, int* cursor, float* dinv) {
  int i = blockIdx.x * blockDim.x + threadIdx.x;
  if (i >= NN) return;
  int b = i >> 8;
  int pref = (b > 0) ? bsum[b - 1] : 0;
  int excl = pref + incl[i] - deg[i];
  rowStart[i] = excl;
  cursor[i] = excl;
  dinv[i] = rsqrtf((float)(deg[i] + 1));  // +1 = self-loop; deg_total >= 1 always
}

__global__ void k_fill(const int* src, const int* dst, int* cursor, int* srcList) {
  int e = blockIdx.x * blockDim.x + threadIdx.x;
  if (e >= EE) return;
  int d = dst[e];
  int p = atomicAdd(&cursor[d], 1);
  srcList[p] = src[e];
}

__global__ void k_cvt_x(const float4* x, ushort4* xb) {
  int i = blockIdx.x * blockDim.x + threadIdx.x;
  if (i >= NN * DD / 4) return;
  float4 v = x[i];
  ushort4 o;
  o.x = f2bf(v.x); o.y = f2bf(v.y); o.z = f2bf(v.z); o.w = f2bf(v.w);
  xb[i] = o;
}

// Transposed bf16 weights: Wt[n][k] so B-frag loads are contiguous 16B
__global__ void k_cvt_w(const float* Wg, const float* Wl,
                        unsigned short* Wgt, unsigned short* Wlt) {
  int i = blockIdx.x * blockDim.x + threadIdx.x;
  if (i >= DD * DD) return;
  int k = i >> 7, n = i & 127;
  Wgt[n * DD + k] = f2bf(Wg[k * DD + n]);
  Wlt[n * DD + k] = f2bf(Wl[k * DD + n]);
}

// Fused dual matmul: hs = (x @ W_gcn) * dinv[row], x2 = x @ W_lin
// Wave = 16 rows x 128 cols; block = 4 waves = 64 rows.
__global__ __launch_bounds__(256) void k_matmul(
    const unsigned short* __restrict__ xb,
    const unsigned short* __restrict__ Wgt,
    const unsigned short* __restrict__ Wlt,
    const float* __restrict__ dinv,
    float* __restrict__ hs, float* __restrict__ x2) {
  int t = threadIdx.x;
  int w = t >> 6, lane = t & 63;
  int quad = lane >> 4, r = lane & 15;
  int m0 = (blockIdx.x * 4 + w) * 16;
  f32x4 zero = {0.f, 0.f, 0.f, 0.f};
  f32x4 accG[8], accL[8];
#pragma unroll
  for (int i = 0; i < 8; i++) { accG[i] = zero; accL[i] = zero; }
  int rowA = m0 + r;
  if (rowA > NN - 1) rowA = NN - 1;  // clamp; stores are guarded
  const unsigned short* xrow = xb + (size_t)rowA * DD + quad * 8;
#pragma unroll
  for (int ks = 0; ks < 4; ks++) {
    bf16x8 a = *(const bf16x8*)(xrow + ks * 32);
#pragma unroll
    for (int nt = 0; nt < 8; nt++) {
      const unsigned short* wgp = Wgt + (size_t)(nt * 16 + r) * DD + ks * 32 + quad * 8;
      const unsigned short* wlp = Wlt + (size_t)(nt * 16 + r) * DD + ks * 32 + quad * 8;
      bf16x8 bg = *(const bf16x8*)wgp;
      bf16x8 bl = *(const bf16x8*)wlp;
      accG[nt] = __builtin_amdgcn_mfma_f32_16x16x32_bf16(a, bg, accG[nt], 0, 0, 0);
      accL[nt] = __builtin_amdgcn_mfma_f32_16x16x32_bf16(a, bl, accL[nt], 0, 0, 0);
    }
  }
  // C/D layout: col = lane&15 (+16*nt), row = quad*4 + reg (+m0)
#pragma unroll
  for (int reg = 0; reg < 4; reg++) {
    int row = m0 + quad * 4 + reg;
    if (row < NN) {
      float di = dinv[row];
#pragma unroll
      for (int nt = 0; nt < 8; nt++) {
        int col = nt * 16 + r;
        hs[(size_t)row * DD + col] = accG[nt][reg] * di;
        x2[(size_t)row * DD + col] = accL[nt][reg];
      }
    }
  }
}

// One wave per node: gather-sum hs[src] over CSR list, then fused LayerNorm.
__global__ __launch_bounds__(256) void k_agg_ln(
    const float* __restrict__ hs, const float* __restrict__ x2,
    const float* __restrict__ dinv, const int* __restrict__ rowStart,
    const int* __restrict__ deg, const int* __restrict__ srcList,
    const float* __restrict__ b_gcn, const float* __restrict__ ln_w,
    const float* __restrict__ ln_b, float* __restrict__ out) {
  int t = threadIdx.x;
  int w = t >> 6, lane = t & 63;
  int node = blockIdx.x * 4 + w;
  if (node >= NN) return;
  int c0 = lane * 2;
  float2 h0 = *(const float2*)(hs + (size_t)node * DD + c0);  // self-loop term
  float a0 = h0.x, a1 = h0.y;
  int start = rowStart[node];
  int cnt = deg[node];
  for (int base = 0; base < cnt; base += 64) {
    int e = base + lane;
    int sj = (e < cnt) ? srcList[start + e] : 0;
    int m = cnt - base; if (m > 64) m = 64;
    for (int j = 0; j < m; ++j) {
      int s = __shfl(sj, j);
      float2 hv = *(const float2*)(hs + (size_t)s * DD + c0);
      a0 += hv.x; a1 += hv.y;
    }
  }
  float di = dinv[node];
  float2 xv = *(const float2*)(x2 + (size_t)node * DD + c0);
  float2 bg = *(const float2*)(b_gcn + c0);
  float y0 = di * a0 + bg.x + xv.x + 1e-6f;
  float y1 = di * a1 + bg.y + xv.y + 1e-6f;
  float s1 = y0 + y1;
  float s2 = y0 * y0 + y1 * y1;
  for (int off = 32; off > 0; off >>= 1) {
    s1 += __shfl_xor(s1, off);
    s2 += __shfl_xor(s2, off);
  }
  float mu = s1 * (1.0f / 128.0f);
  float var = s2 * (1.0f / 128.0f) - mu * mu;
  float inv = rsqrtf(var + 1e-5f);
  float2 lw = *(const float2*)(ln_w + c0);
  float2 lb = *(const float2*)(ln_b + c0);
  float2 o;
  o.x = (y0 - mu) * inv * lw.x + lb.x;
  o.y = (y1 - mu) * inv * lw.y + lb.y;
  *(float2*)(out + (size_t)node * DD + c0) = o;
}

extern "C" void kernel_launch(void* const* d_in, const int* in_sizes, int n_in,
                              void* d_out, int out_size, void* d_ws, size_t ws_size,
                              hipStream_t stream) {
  const int* adj = (const int*)d_in[0];     // [2, E]
  const float* x = (const float*)d_in[1];   // [N, 128]
  const float* Wg = (const float*)d_in[2];  // [128, 128]
  const float* bg = (const float*)d_in[3];  // [128]
  const float* Wl = (const float*)d_in[4];  // [128, 128]
  const float* lw = (const float*)d_in[5];  // [128]
  const float* lb = (const float*)d_in[6];  // [128]
  const int* srcp = adj;
  const int* dstp = adj + EE;
  float* out = (float*)d_out;

  char* ws = (char*)d_ws;
  size_t off = 0;
  auto alloc = [&](size_t bytes) -> void* {
    void* p = ws + off;
    off += (bytes + 255) & ~(size_t)255;
    return p;
  };
  int* deg = (int*)alloc((size_t)NN * 4);
  int* incl = (int*)alloc((size_t)NN * 4);
  int* bsum = (int*)alloc(1024);
  int* rowStart = (int*)alloc((size_t)NN * 4);
  int* cursor = (int*)alloc((size_t)NN * 4);
  float* dinv = (float*)alloc((size_t)NN * 4);
  int* srcList = (int*)alloc((size_t)EE * 4);
  unsigned short* xb = (unsigned short*)alloc((size_t)NN * DD * 2);
  unsigned short* Wgt = (unsigned short*)alloc((size_t)DD * DD * 2);
  unsigned short* Wlt = (unsigned short*)alloc((size_t)DD * DD * 2);
  float* hs = (float*)alloc((size_t)NN * DD * 4);
  float* x2 = (float*)alloc((size_t)NN * DD * 4);
  (void)ws_size; (void)in_sizes; (void)n_in; (void)out_size;

  int nb = (NN + 255) / 256;  // 196
  k_zero_deg<<<nb, 256, 0, stream>>>(deg);
  k_deg<<<(EE + 255) / 256, 256, 0, stream>>>(dstp, deg);
  k_scan1<<<nb, 256, 0, stream>>>(deg, incl, bsum);
  k_scan2<<<1, 256, 0, stream>>>(bsum, nb);
  k_scan3<<<nb, 256, 0, stream>>>(deg, incl, bsum, rowStart, cursor, dinv);
  k_fill<<<(EE + 255) / 256, 256, 0, stream>>>(srcp, dstp, cursor, srcList);
  k_cvt_x<<<(NN * DD / 4 + 255) / 256, 256, 0, stream>>>((const float4*)x, (ushort4*)xb);
  k_cvt_w<<<(DD * DD + 255) / 256, 256, 0, stream>>>(Wg, Wl, Wgt, Wlt);
  k_matmul<<<(NN + 63) / 64, 256, 0, stream>>>(xb, Wgt, Wlt, dinv, hs, x2);
  k_agg_ln<<<(NN + 3) / 4, 256, 0, stream>>>(hs, x2, dinv, rowStart, deg, srcList,
                                             bg, lw, lb, out);
}

// Round 2
// 262.956 us; speedup vs baseline: 1.0696x; 1.0696x over previous
//
#include <hip/hip_runtime.h>
#include <hip/hip_bf16.h>

#define NN 50000
#define EE 800000
#define DD 128

typedef __attribute__((ext_vector_type(8))) short bf16x8;
typedef __attribute__((ext_vector_type(4))) float f32x4;

static __device__ __forceinline__ unsigned short f2bf(float f) {
  union { float f; unsigned u; } v; v.f = f;
  unsigned r = v.u + 0x7FFFu + ((v.u >> 16) & 1u);
  return (unsigned short)(r >> 16);
}
static __device__ __forceinline__ float bf2f(unsigned short h) {
  union { unsigned u; float f; } v; v.u = ((unsigned)h) << 16;
  return v.f;
}

__global__ void k_deg(const int* __restrict__ dst, int* __restrict__ deg) {
  int e = blockIdx.x * blockDim.x + threadIdx.x;
  if (e < EE) atomicAdd(&deg[dst[e]], 1);
}

// Per-block inclusive scan (Hillis-Steele over 256)
__global__ void k_scan1(const int* __restrict__ deg, int* __restrict__ incl,
                        int* __restrict__ bsum) {
  __shared__ int s[256];
  int t = threadIdx.x;
  int i = blockIdx.x * 256 + t;
  int v = (i < NN) ? deg[i] : 0;
  s[t] = v;
  for (int off = 1; off < 256; off <<= 1) {
    __syncthreads();
    int tmp = (t >= off) ? s[t - off] : 0;
    __syncthreads();
    if (t >= off) s[t] += tmp;
  }
  __syncthreads();
  if (i < NN) incl[i] = s[t];
  if (t == 255) bsum[blockIdx.x] = s[255];
}

__global__ void k_scan2(int* bsum, int nb) {
  __shared__ int s[256];
  int t = threadIdx.x;
  int v = (t < nb) ? bsum[t] : 0;
  s[t] = v;
  for (int off = 1; off < 256; off <<= 1) {
    __syncthreads();
    int tmp = (t >= off) ? s[t - off] : 0;
    __syncthreads();
    if (t >= off) s[t] += tmp;
  }
  if (t < nb) bsum[t] = s[t];
}

__global__ void k_scan3(const int* __restrict__ deg, const int* __restrict__ incl,
                        const int* __restrict__ bsum, int* __restrict__ rowStart,
                        int* __restrict__ cursor, float* __restrict__ dinv) {
  int i = blockIdx.x * blockDim.x + threadIdx.x;
  if (i >= NN) return;
  int b = i >> 8;
  int pref = (b > 0) ? bsum[b - 1] : 0;
  int excl = pref + incl[i] - deg[i];
  rowStart[i] = excl;
  cursor[i] = excl;
  dinv[i] = rsqrtf((float)(deg[i] + 1));  // +1 self-loop; always >= 1
}

__global__ void k_fill(const int* __restrict__ src, const int* __restrict__ dst,
                       int* __restrict__ cursor, int* __restrict__ srcList) {
  int e = blockIdx.x * blockDim.x + threadIdx.x;
  if (e >= EE) return;
  int d = dst[e];
  int p = atomicAdd(&cursor[d], 1);
  srcList[p] = src[e];
}

// xs[i] = dinv[i]*x[i] (bf16, gather operand); axc[i][128:256] = x[i] (bf16, A right half)
__global__ void k_cvt_x(const float4* __restrict__ x, const float* __restrict__ dinv,
                        ushort4* __restrict__ xsv, unsigned short* __restrict__ axc) {
  int i = blockIdx.x * blockDim.x + threadIdx.x;
  if (i >= NN * DD / 4) return;
  float4 v = x[i];
  int node = i >> 5;   // 32 float4 per row
  int c4 = i & 31;
  float di = dinv[node];
  ushort4 s, rw;
  s.x = f2bf(v.x * di); s.y = f2bf(v.y * di);
  s.z = f2bf(v.z * di); s.w = f2bf(v.w * di);
  rw.x = f2bf(v.x); rw.y = f2bf(v.y); rw.z = f2bf(v.z); rw.w = f2bf(v.w);
  xsv[i] = s;
  *(ushort4*)(axc + (size_t)node * 256 + 128 + c4 * 4) = rw;
}

// Wt[n][k] combined: k<128 -> W_gcn[k][n]; k>=128 -> W_lin[k-128][n]
__global__ void k_cvt_w(const float* __restrict__ Wg, const float* __restrict__ Wl,
                        unsigned short* __restrict__ Wt) {
  int i = blockIdx.x * blockDim.x + threadIdx.x;
  if (i >= DD * 256) return;
  int n = i >> 8, k = i & 255;
  float v = (k < 128) ? Wg[k * DD + n] : Wl[(k - 128) * DD + n];
  Wt[i] = f2bf(v);
}

// One wave per node: 4 groups x 16 lanes; each group keeps an independent
// row-load in flight (4x MLP vs round-1). Writes agg (bf16) into axc[:, :128].
__global__ __launch_bounds__(256) void k_agg(
    const unsigned short* __restrict__ xs, const float* __restrict__ dinv,
    const int* __restrict__ rowStart, const int* __restrict__ deg,
    const int* __restrict__ srcList, unsigned short* __restrict__ axc) {
  int t = threadIdx.x;
  int w = t >> 6, lane = t & 63;
  int node = blockIdx.x * 4 + w;
  if (node >= NN) return;
  int g = lane >> 4, r = lane & 15;
  int c0 = r * 8;  // 8 bf16 cols per lane
  float acc[8];
#pragma unroll
  for (int i = 0; i < 8; i++) acc[i] = 0.f;
  if (g == 0) {  // self-loop term
    bf16x8 v = *(const bf16x8*)(xs + (size_t)node * DD + c0);
#pragma unroll
    for (int i = 0; i < 8; i++) acc[i] = bf2f(((unsigned short)v[i]));
  }
  int start = rowStart[node], cnt = deg[node];
  int j = g;
  int s = (j < cnt) ? srcList[start + j] : 0;
  while (j < cnt) {
    int jn = j + 4;
    int sn = (jn < cnt) ? srcList[start + jn] : 0;  // prefetch next index
    bf16x8 v = *(const bf16x8*)(xs + (size_t)s * DD + c0);
#pragma unroll
    for (int i = 0; i < 8; i++) acc[i] += bf2f(((unsigned short)v[i]));
    j = jn; s = sn;
  }
  // combine the 4 groups
#pragma unroll
  for (int i = 0; i < 8; i++) {
    acc[i] += __shfl_xor(acc[i], 16);
    acc[i] += __shfl_xor(acc[i], 32);
  }
  if (g == 0) {
    float di = dinv[node];
    bf16x8 o;
#pragma unroll
    for (int i = 0; i < 8; i++) o[i] = (short)f2bf(acc[i] * di);
    *(bf16x8*)(axc + (size_t)node * 256 + c0) = o;
  }
}

// Fused matmul + bias + LayerNorm. A = axc [N][256] bf16, B^T = Wt [128][256].
// Wave = 16 rows x 128 cols. out = LN(A@Wcomb + b_gcn + 1e-6)*lnw + lnb.
__global__ __launch_bounds__(256) void k_mm_ln(
    const unsigned short* __restrict__ axc, const unsigned short* __restrict__ Wt,
    const float* __restrict__ bgcn, const float* __restrict__ lnw,
    const float* __restrict__ lnb, float* __restrict__ out) {
  int t = threadIdx.x;
  int w = t >> 6, lane = t & 63;
  int quad = lane >> 4, r = lane & 15;
  int m0 = (blockIdx.x * 4 + w) * 16;
  f32x4 zero = {0.f, 0.f, 0.f, 0.f};
  f32x4 acc[8];
#pragma unroll
  for (int i = 0; i < 8; i++) acc[i] = zero;
  int rowA = m0 + r;
  if (rowA > NN - 1) rowA = NN - 1;  // clamp; stores guarded
  const unsigned short* arow = axc + (size_t)rowA * 256 + quad * 8;
#pragma unroll
  for (int ks = 0; ks < 8; ks++) {
    bf16x8 a = *(const bf16x8*)(arow + ks * 32);
#pragma unroll
    for (int nt = 0; nt < 8; nt++) {
      bf16x8 b = *(const bf16x8*)(Wt + (size_t)(nt * 16 + r) * 256 + ks * 32 + quad * 8);
      acc[nt] = __builtin_amdgcn_mfma_f32_16x16x32_bf16(a, b, acc[nt], 0, 0, 0);
    }
  }
  // per-lane epilogue params for its 8 cols (col = nt*16 + r)
  float bg[8], lw[8], lb[8];
#pragma unroll
  for (int nt = 0; nt < 8; nt++) {
    int col = nt * 16 + r;
    bg[nt] = bgcn[col] + 1e-6f;
    lw[nt] = lnw[col];
    lb[nt] = lnb[col];
  }
  // C/D layout: row = m0 + quad*4 + reg, col = nt*16 + r
#pragma unroll
  for (int reg = 0; reg < 4; reg++) {
    float y[8];
    float s1 = 0.f, s2 = 0.f;
#pragma unroll
    for (int nt = 0; nt < 8; nt++) {
      y[nt] = acc[nt][reg] + bg[nt];
      s1 += y[nt];
      s2 += y[nt] * y[nt];
    }
    // reduce across the 16 lanes of this quad (xor bits 0..3)
#pragma unroll
    for (int off = 1; off < 16; off <<= 1) {
      s1 += __shfl_xor(s1, off);
      s2 += __shfl_xor(s2, off);
    }
    float mu = s1 * (1.0f / 128.0f);
    float var = s2 * (1.0f / 128.0f) - mu * mu;
    float inv = rsqrtf(var + 1e-5f);
    int row = m0 + quad * 4 + reg;
    if (row < NN) {
#pragma unroll
      for (int nt = 0; nt < 8; nt++) {
        out[(size_t)row * DD + nt * 16 + r] = (y[nt] - mu) * inv * lw[nt] + lb[nt];
      }
    }
  }
}

extern "C" void kernel_launch(void* const* d_in, const int* in_sizes, int n_in,
                              void* d_out, int out_size, void* d_ws, size_t ws_size,
                              hipStream_t stream) {
  const int* adj = (const int*)d_in[0];     // [2, E]
  const float* x = (const float*)d_in[1];   // [N, 128]
  const float* Wg = (const float*)d_in[2];  // [128, 128]
  const float* bg = (const float*)d_in[3];  // [128]
  const float* Wl = (const float*)d_in[4];  // [128, 128]
  const float* lw = (const float*)d_in[5];  // [128]
  const float* lb = (const float*)d_in[6];  // [128]
  const int* srcp = adj;
  const int* dstp = adj + EE;
  float* out = (float*)d_out;

  char* ws = (char*)d_ws;
  size_t off = 0;
  auto alloc = [&](size_t bytes) -> void* {
    void* p = ws + off;
    off += (bytes + 255) & ~(size_t)255;
    return p;
  };
  int* deg = (int*)alloc((size_t)NN * 4);
  int* incl = (int*)alloc((size_t)NN * 4);
  int* bsum = (int*)alloc(1024);
  int* rowStart = (int*)alloc((size_t)NN * 4);
  int* cursor = (int*)alloc((size_t)NN * 4);
  float* dinv = (float*)alloc((size_t)NN * 4);
  int* srcList = (int*)alloc((size_t)EE * 4);
  unsigned short* xs = (unsigned short*)alloc((size_t)NN * DD * 2);
  unsigned short* axc = (unsigned short*)alloc((size_t)NN * 256 * 2);
  unsigned short* Wt = (unsigned short*)alloc((size_t)DD * 256 * 2);
  (void)ws_size; (void)in_sizes; (void)n_in; (void)out_size;

  int nb = (NN + 255) / 256;  // 196
  hipMemsetAsync(deg, 0, (size_t)NN * 4, stream);
  k_deg<<<(EE + 255) / 256, 256, 0, stream>>>(dstp, deg);
  k_scan1<<<nb, 256, 0, stream>>>(deg, incl, bsum);
  k_scan2<<<1, 256, 0, stream>>>(bsum, nb);
  k_scan3<<<nb, 256, 0, stream>>>(deg, incl, bsum, rowStart, cursor, dinv);
  k_fill<<<(EE + 255) / 256, 256, 0, stream>>>(srcp, dstp, cursor, srcList);
  k_cvt_x<<<(NN * DD / 4 + 255) / 256, 256, 0, stream>>>((const float4*)x, dinv,
                                                         (ushort4*)xs, axc);
  k_cvt_w<<<(DD * 256 + 255) / 256, 256, 0, stream>>>(Wg, Wl, Wt);
  k_agg<<<(NN + 3) / 4, 256, 0, stream>>>(xs, dinv, rowStart, deg, srcList, axc);
  k_mm_ln<<<(NN + 63) / 64, 256, 0, stream>>>(axc, Wt, bg, lw, lb, out);
}

// Round 3
// 208.418 us; speedup vs baseline: 1.3495x; 1.2617x over previous
//
#include <hip/hip_runtime.h>
#include <hip/hip_bf16.h>

#define NN 50000
#define EE 800000
#define DD 128
#define NB 196   // ceil(50000/256) buckets of 256 nodes

typedef __attribute__((ext_vector_type(8))) short bf16x8;
typedef __attribute__((ext_vector_type(4))) float f32x4;

static __device__ __forceinline__ unsigned short f2bf(float f) {
  union { float f; unsigned u; } v; v.f = f;
  unsigned r = v.u + 0x7FFFu + ((v.u >> 16) & 1u);
  return (unsigned short)(r >> 16);
}
static __device__ __forceinline__ float bf2f(unsigned short h) {
  union { unsigned u; float f; } v; v.u = ((unsigned)h) << 16;
  return v.f;
}

// blocks 0..195: LDS-aggregated bucket histogram of dst>>8.
// blocks 196..227: convert W_gcn/W_lin -> combined transposed bf16 Wt[128][256].
__global__ __launch_bounds__(256) void k_p0(const int* __restrict__ dst,
                                            int* __restrict__ bucketCnt,
                                            const float* __restrict__ Wg,
                                            const float* __restrict__ Wl,
                                            unsigned short* __restrict__ Wt) {
  int b = blockIdx.x, t = threadIdx.x;
  if (b < NB) {
    __shared__ int cnt[NB];
    for (int i = t; i < NB; i += 256) cnt[i] = 0;
    __syncthreads();
    int e0 = b * 4096;
    for (int i = t; i < 4096; i += 256) {
      int e = e0 + i;
      if (e < EE) atomicAdd(&cnt[dst[e] >> 8], 1);
    }
    __syncthreads();
    for (int i = t; i < NB; i += 256)
      if (cnt[i]) atomicAdd(&bucketCnt[i], cnt[i]);
  } else {
    for (int i = (b - NB) * 256 + t; i < DD * 256; i += 32 * 256) {
      int n = i >> 8, k = i & 255;
      float v = (k < 128) ? Wg[k * DD + n] : Wl[(k - 128) * DD + n];
      Wt[i] = f2bf(v);
    }
  }
}

// single block: exclusive scan of bucketCnt -> bucketStart; init cursor.
__global__ __launch_bounds__(256) void k_pscan(const int* __restrict__ bucketCnt,
                                               int* __restrict__ bucketStart,
                                               int* __restrict__ cursor) {
  __shared__ int s[256];
  int t = threadIdx.x;
  int v = (t < NB) ? bucketCnt[t] : 0;
  s[t] = v;
  for (int off = 1; off < 256; off <<= 1) {
    __syncthreads();
    int tmp = (t >= off) ? s[t - off] : 0;
    __syncthreads();
    if (t >= off) s[t] += tmp;
  }
  __syncthreads();
  if (t < NB) {
    int excl = s[t] - v;
    bucketStart[t] = excl;
    cursor[t] = excl;
  }
}

// Stage 4096 edges in LDS, bin by bucket, reserve contiguous runs (1 atomic
// per bucket per block), write packed records: src | dlocal<<16 | bucket<<24.
__global__ __launch_bounds__(256) void k_p1(const int* __restrict__ src,
                                            const int* __restrict__ dst,
                                            int* __restrict__ cursor,
                                            unsigned int* __restrict__ pairs) {
  __shared__ unsigned int stage[4096];
  __shared__ int cnt[NB], base[NB], cur[NB];
  int t = threadIdx.x;
  int e0 = blockIdx.x * 4096;
  for (int i = t; i < NB; i += 256) { cnt[i] = 0; cur[i] = 0; }
  __syncthreads();
  for (int i = t; i < 4096; i += 256) {
    int e = e0 + i;
    unsigned int p = 0xFFFFFFFFu;
    if (e < EE) {
      int d = dst[e];
      int s = src[e];
      int bk = d >> 8;
      p = (unsigned int)s | ((unsigned int)(d & 255) << 16) | ((unsigned int)bk << 24);
      atomicAdd(&cnt[bk], 1);
    }
    stage[i] = p;
  }
  __syncthreads();
  for (int i = t; i < NB; i += 256)
    base[i] = cnt[i] ? atomicAdd(&cursor[i], cnt[i]) : 0;
  __syncthreads();
  for (int i = t; i < 4096; i += 256) {
    unsigned int p = stage[i];
    if (p != 0xFFFFFFFFu) {
      int bk = p >> 24;
      int ofs = atomicAdd(&cur[bk], 1);
      pairs[base[bk] + ofs] = p;
    }
  }
}

// One block per bucket (256 nodes): degree count + scan -> deg/dinv/rowStart,
// scatter srcList within block-private region, then convert x rows for these
// nodes (xs = dinv*x bf16; axc right half = x bf16).
__global__ __launch_bounds__(256) void k_p2(
    const unsigned int* __restrict__ pairs, const int* __restrict__ bucketStart,
    const int* __restrict__ bucketCnt, const float4* __restrict__ x4,
    int* __restrict__ deg, float* __restrict__ dinv, int* __restrict__ rowStart,
    int* __restrict__ srcList, ushort4* __restrict__ xs4,
    ushort4* __restrict__ axc4) {
  int b = blockIdx.x, t = threadIdx.x;
  __shared__ int ldeg[256], lscan[256], lcur[256];
  __shared__ float ldinv[256];
  int n0 = b << 8;
  int nloc = NN - n0; if (nloc > 256) nloc = 256;
  int start = bucketStart[b], cnt = bucketCnt[b];
  ldeg[t] = 0;
  __syncthreads();
  for (int i = t; i < cnt; i += 256)
    atomicAdd(&ldeg[(pairs[start + i] >> 16) & 255], 1);
  __syncthreads();
  int dg = ldeg[t];
  lscan[t] = dg;
  for (int off = 1; off < 256; off <<= 1) {
    __syncthreads();
    int tmp = (t >= off) ? lscan[t - off] : 0;
    __syncthreads();
    if (t >= off) lscan[t] += tmp;
  }
  __syncthreads();
  int rs = start + lscan[t] - dg;
  lcur[t] = rs;
  float di = rsqrtf((float)(dg + 1));
  ldinv[t] = di;
  if (t < nloc) {
    deg[n0 + t] = dg;
    dinv[n0 + t] = di;
    rowStart[n0 + t] = rs;
  }
  __syncthreads();
  for (int i = t; i < cnt; i += 256) {
    unsigned int p = pairs[start + i];
    int pos = atomicAdd(&lcur[(p >> 16) & 255], 1);
    srcList[pos] = (int)(p & 0xFFFFu);
  }
  // phase C: convert x rows for nodes [n0, n0+nloc)
  for (int i = t; i < nloc * 32; i += 256) {
    int r = i >> 5, c4 = i & 31;
    float4 v = x4[(size_t)(n0 + r) * 32 + c4];
    float d = ldinv[r];
    ushort4 s, rw;
    s.x = f2bf(v.x * d); s.y = f2bf(v.y * d);
    s.z = f2bf(v.z * d); s.w = f2bf(v.w * d);
    rw.x = f2bf(v.x); rw.y = f2bf(v.y); rw.z = f2bf(v.z); rw.w = f2bf(v.w);
    xs4[(size_t)(n0 + r) * 32 + c4] = s;
    axc4[(size_t)(n0 + r) * 64 + 32 + c4] = rw;
  }
}

// One wave per node; 4 groups x 16 lanes; 2 rows in flight per group (8/wave)
// + next-index prefetch. Writes agg (bf16) into axc[:, :128].
__global__ __launch_bounds__(256) void k_agg(
    const unsigned short* __restrict__ xs, const float* __restrict__ dinv,
    const int* __restrict__ rowStart, const int* __restrict__ deg,
    const int* __restrict__ srcList, unsigned short* __restrict__ axc) {
  int t = threadIdx.x;
  int w = t >> 6, lane = t & 63;
  int node = blockIdx.x * 4 + w;
  if (node >= NN) return;
  int g = lane >> 4, r = lane & 15;
  int c0 = r * 8;
  float acc[8];
#pragma unroll
  for (int i = 0; i < 8; i++) acc[i] = 0.f;
  if (g == 0) {  // self-loop term
    bf16x8 v = *(const bf16x8*)(xs + (size_t)node * DD + c0);
#pragma unroll
    for (int i = 0; i < 8; i++) acc[i] = bf2f((unsigned short)v[i]);
  }
  int start = rowStart[node], cnt = deg[node];
  int j0 = 2 * g, j1 = 2 * g + 1;
  int s0 = (j0 < cnt) ? srcList[start + j0] : -1;
  int s1 = (j1 < cnt) ? srcList[start + j1] : -1;
  for (int base = 0; base < cnt; base += 8) {
    int n0 = base + 8 + 2 * g, n1 = n0 + 1;
    int t0 = (n0 < cnt) ? srcList[start + n0] : -1;
    int t1 = (n1 < cnt) ? srcList[start + n1] : -1;
    if (s0 >= 0) {
      bf16x8 v = *(const bf16x8*)(xs + (size_t)s0 * DD + c0);
#pragma unroll
      for (int i = 0; i < 8; i++) acc[i] += bf2f((unsigned short)v[i]);
    }
    if (s1 >= 0) {
      bf16x8 v = *(const bf16x8*)(xs + (size_t)s1 * DD + c0);
#pragma unroll
      for (int i = 0; i < 8; i++) acc[i] += bf2f((unsigned short)v[i]);
    }
    s0 = t0; s1 = t1;
  }
#pragma unroll
  for (int i = 0; i < 8; i++) {
    acc[i] += __shfl_xor(acc[i], 16);
    acc[i] += __shfl_xor(acc[i], 32);
  }
  if (g == 0) {
    float di = dinv[node];
    bf16x8 o;
#pragma unroll
    for (int i = 0; i < 8; i++) o[i] = (short)f2bf(acc[i] * di);
    *(bf16x8*)(axc + (size_t)node * 256 + c0) = o;
  }
}

// Fused matmul + bias + LayerNorm. A = axc [N][256] bf16, B^T = Wt [128][256].
__global__ __launch_bounds__(256) void k_mm_ln(
    const unsigned short* __restrict__ axc, const unsigned short* __restrict__ Wt,
    const float* __restrict__ bgcn, const float* __restrict__ lnw,
    const float* __restrict__ lnb, float* __restrict__ out) {
  int t = threadIdx.x;
  int w = t >> 6, lane = t & 63;
  int quad = lane >> 4, r = lane & 15;
  int m0 = (blockIdx.x * 4 + w) * 16;
  f32x4 zero = {0.f, 0.f, 0.f, 0.f};
  f32x4 acc[8];
#pragma unroll
  for (int i = 0; i < 8; i++) acc[i] = zero;
  int rowA = m0 + r;
  if (rowA > NN - 1) rowA = NN - 1;  // clamp; stores guarded
  const unsigned short* arow = axc + (size_t)rowA * 256 + quad * 8;
#pragma unroll
  for (int ks = 0; ks < 8; ks++) {
    bf16x8 a = *(const bf16x8*)(arow + ks * 32);
#pragma unroll
    for (int nt = 0; nt < 8; nt++) {
      bf16x8 b = *(const bf16x8*)(Wt + (size_t)(nt * 16 + r) * 256 + ks * 32 + quad * 8);
      acc[nt] = __builtin_amdgcn_mfma_f32_16x16x32_bf16(a, b, acc[nt], 0, 0, 0);
    }
  }
  float bg[8], lw[8], lb[8];
#pragma unroll
  for (int nt = 0; nt < 8; nt++) {
    int col = nt * 16 + r;
    bg[nt] = bgcn[col] + 1e-6f;
    lw[nt] = lnw[col];
    lb[nt] = lnb[col];
  }
#pragma unroll
  for (int reg = 0; reg < 4; reg++) {
    float y[8];
    float s1 = 0.f, s2 = 0.f;
#pragma unroll
    for (int nt = 0; nt < 8; nt++) {
      y[nt] = acc[nt][reg] + bg[nt];
      s1 += y[nt];
      s2 += y[nt] * y[nt];
    }
#pragma unroll
    for (int off = 1; off < 16; off <<= 1) {
      s1 += __shfl_xor(s1, off);
      s2 += __shfl_xor(s2, off);
    }
    float mu = s1 * (1.0f / 128.0f);
    float var = s2 * (1.0f / 128.0f) - mu * mu;
    float inv = rsqrtf(var + 1e-5f);
    int row = m0 + quad * 4 + reg;
    if (row < NN) {
#pragma unroll
      for (int nt = 0; nt < 8; nt++) {
        out[(size_t)row * DD + nt * 16 + r] = (y[nt] - mu) * inv * lw[nt] + lb[nt];
      }
    }
  }
}

extern "C" void kernel_launch(void* const* d_in, const int* in_sizes, int n_in,
                              void* d_out, int out_size, void* d_ws, size_t ws_size,
                              hipStream_t stream) {
  const int* adj = (const int*)d_in[0];     // [2, E]
  const float* x = (const float*)d_in[1];   // [N, 128]
  const float* Wg = (const float*)d_in[2];  // [128, 128]
  const float* bg = (const float*)d_in[3];  // [128]
  const float* Wl = (const float*)d_in[4];  // [128, 128]
  const float* lw = (const float*)d_in[5];  // [128]
  const float* lb = (const float*)d_in[6];  // [128]
  const int* srcp = adj;
  const int* dstp = adj + EE;
  float* out = (float*)d_out;

  char* ws = (char*)d_ws;
  size_t off = 0;
  auto alloc = [&](size_t bytes) -> void* {
    void* p = ws + off;
    off += (bytes + 255) & ~(size_t)255;
    return p;
  };
  int* bucketCnt = (int*)alloc(NB * 4);
  int* bucketStart = (int*)alloc(NB * 4);
  int* cursor = (int*)alloc(NB * 4);
  unsigned int* pairs = (unsigned int*)alloc((size_t)EE * 4);
  int* deg = (int*)alloc((size_t)NN * 4);
  float* dinv = (float*)alloc((size_t)NN * 4);
  int* rowStart = (int*)alloc((size_t)NN * 4);
  int* srcList = (int*)alloc((size_t)EE * 4);
  unsigned short* xs = (unsigned short*)alloc((size_t)NN * DD * 2);
  unsigned short* axc = (unsigned short*)alloc((size_t)NN * 256 * 2);
  unsigned short* Wt = (unsigned short*)alloc((size_t)DD * 256 * 2);
  (void)ws_size; (void)in_sizes; (void)n_in; (void)out_size;

  hipMemsetAsync(bucketCnt, 0, NB * 4, stream);
  k_p0<<<NB + 32, 256, 0, stream>>>(dstp, bucketCnt, Wg, Wl, Wt);
  k_pscan<<<1, 256, 0, stream>>>(bucketCnt, bucketStart, cursor);
  k_p1<<<NB, 256, 0, stream>>>(srcp, dstp, cursor, pairs);
  k_p2<<<NB, 256, 0, stream>>>(pairs, bucketStart, bucketCnt, (const float4*)x,
                               deg, dinv, rowStart, srcList, (ushort4*)xs,
                               (ushort4*)axc);
  k_agg<<<(NN + 3) / 4, 256, 0, stream>>>(xs, dinv, rowStart, deg, srcList, axc);
  k_mm_ln<<<(NN + 63) / 64, 256, 0, stream>>>(axc, Wt, bg, lw, lb, out);
}